// Round 4
// baseline (218.567 us; speedup 1.0000x reference)
//
#include <hip/hip_runtime.h>
#include <hip/hip_bf16.h>

typedef __attribute__((ext_vector_type(8))) short v8s;
typedef __attribute__((ext_vector_type(4))) short v4s;
typedef __attribute__((ext_vector_type(4))) float v4f;
typedef __attribute__((ext_vector_type(8))) float v8f;
typedef __attribute__((ext_vector_type(16))) float v16f;

#define NB 4
#define NN 4096
#define ND 256
#define NH 4
#define NHD 64

__device__ __forceinline__ short f2bs(float f) {
  union { __hip_bfloat16 h; short s; } u;
  u.h = __float2bfloat16(f);
  return u.s;
}
__device__ __forceinline__ short f2bs_fast(float f) {
  unsigned u = __float_as_uint(f);
  return (short)((u + 0x7fffu + ((u >> 16) & 1u)) >> 16);
}
__device__ __forceinline__ float fexp2(float x) {
#if __has_builtin(__builtin_amdgcn_exp2f)
  return __builtin_amdgcn_exp2f(x);
#else
  return exp2f(x);
#endif
}
__device__ __forceinline__ unsigned cvt_pk(float lo, float hi) {
  unsigned r;
  asm("v_cvt_pk_bf16_f32 %0, %1, %2" : "=v"(r) : "v"(lo), "v"(hi));
  return r;
}

__device__ __forceinline__ void gload16(const short* g, short* l) {
  __builtin_amdgcn_global_load_lds((const __attribute__((address_space(1))) void*)g,
                                   (__attribute__((address_space(3))) void*)l, 16, 0, 0);
}

// ---------------- K0: cast descriptors fp32 -> bf16 into hbuf[:, 0:256] (ld 512)
__global__ void k_cast(const float* __restrict__ desc, short* __restrict__ hbuf) {
  int i = blockIdx.x * blockDim.x + threadIdx.x;
  const v4f* src = (const v4f*)desc;
  v4f v = src[i];
  int e0 = i << 2;
  int row = e0 >> 8;
  int col = e0 & 255;
  v4s o;
  #pragma unroll
  for (int j = 0; j < 4; ++j) o[j] = f2bs(v[j]);
  *(v4s*)(hbuf + row * 512 + col) = o;
}

// ---------------- K0b: cast weights fp32 -> bf16 (Wqkv | out_w | ffn1_w | ffn2_w)
__global__ void k_wcast(const float* __restrict__ a, const float* __restrict__ b,
                        const float* __restrict__ c, const float* __restrict__ d,
                        short* __restrict__ o) {
  int i = (blockIdx.x * 256 + threadIdx.x) * 8;
  const float* s; int off;
  if (i < 196608)      { s = a; off = 0; }
  else if (i < 262144) { s = b; off = 196608; }
  else if (i < 524288) { s = c; off = 262144; }
  else                 { s = d; off = 524288; }
  v8f v = *(const v8f*)(s + (i - off));
  v8s r;
  #pragma unroll
  for (int j = 0; j < 8; ++j) r[j] = f2bs(v[j]);
  *(v8s*)(o + i) = r;
}

// ---------------- K1: QKV GEMM + fused RoPE (permuted col order)
__global__ __launch_bounds__(256)
void k_qkv(const short* __restrict__ hbuf, const short* __restrict__ Wb,
           const float* __restrict__ bias, const float* __restrict__ kp,
           short* __restrict__ Qb, short* __restrict__ Kb, short* __restrict__ Vt) {
  __shared__ short Al[64 * 32];
  __shared__ short Bl[64 * 32];
  int mt = blockIdx.x, nt = blockIdx.y, tid = threadIdx.x;
  int w = tid >> 6, lane = tid & 63, lg = lane >> 4, lr = lane & 15;
  int srow = tid >> 2, scol8 = (tid & 3) << 3;
  int t_ = nt >> 2, h_ = nt & 3;
  int dS = (nt * 64 + srow) & 63;
  int wrow = h_ * 192 + dS * 3 + t_;
  v4f acc[4] = {};
  for (int kt = 0; kt < 8; ++kt) {
    int k0 = kt * 32;
    v8s av = *(const v8s*)(hbuf + (size_t)(mt * 64 + srow) * 512 + k0 + scol8);
    v8s bv = *(const v8s*)(Wb + (size_t)wrow * 256 + k0 + scol8);
    __syncthreads();
    *(v8s*)(Al + srow * 32 + (scol8 ^ ((srow & 3) << 3))) = av;
    *(v8s*)(Bl + srow * 32 + (scol8 ^ ((srow & 3) << 3))) = bv;
    __syncthreads();
    int ar = w * 16 + lr;
    v8s af = *(const v8s*)(Al + ar * 32 + ((lg * 8) ^ ((ar & 3) << 3)));
    #pragma unroll
    for (int c = 0; c < 4; ++c) {
      int br = c * 16 + lr;
      v8s bf = *(const v8s*)(Bl + br * 32 + ((lg * 8) ^ ((br & 3) << 3)));
      acc[c] = __builtin_amdgcn_mfma_f32_16x16x32_bf16(af, bf, acc[c], 0, 0, 0);
    }
  }
  int grow0 = mt * 64 + w * 16 + lg * 4;
  int b_ = grow0 >> 12, n0 = grow0 & 4095;
  if (t_ == 2) {
    #pragma unroll
    for (int c = 0; c < 4; ++c) {
      int d = c * 16 + lr;
      float bb = bias[h_ * 192 + d * 3 + 2];
      v4s pw;
      #pragma unroll
      for (int j = 0; j < 4; ++j) pw[j] = f2bs(acc[c][j] + bb);
      *(v4s*)(Vt + ((size_t)((b_ * NH + h_) * NHD + d) * NN + n0)) = pw;
    }
  } else {
    float qsc = (t_ == 0) ? 0.125f * 1.44269504088896340736f : 1.0f;
    short* dst = (t_ == 0) ? Qb : Kb;
    #pragma unroll
    for (int c = 0; c < 4; ++c) {
      int d = c * 16 + lr;
      float bb = bias[h_ * 192 + d * 3 + t_];
      #pragma unroll
      for (int j = 0; j < 4; ++j) {
        float x = acc[c][j] + bb;
        float xp = __shfl_xor(x, 1, 64);
        int n_ = n0 + j;
        float cs = kp[((size_t)b_ * NN + n_) * 64 + d];
        float sn = kp[((size_t)(NB + b_) * NN + n_) * 64 + d];
        float ov = (d & 1) ? (x * cs + xp * sn) : (x * cs - xp * sn);
        dst[((size_t)((b_ * NH + h_) * NN + n_)) * 64 + d] = f2bs(ov * qsc);
      }
    }
  }
}

// ---------------- K3: flash attention v4. grid (16, 16), 4 waves, 64 q/wave, 32x32 MFMA.
// S^T = mfma(K, Q): col=lane&31 = q; ctx^T = mfma(V^T, P^T): col=lane&31 = q.
// P stays in registers (cvt_pk + half-exchange); per-lane softmax state.
__global__ __launch_bounds__(256, 1)
void k_attn(const short* __restrict__ Qb, const short* __restrict__ Kb,
            const short* __restrict__ Vt, short* __restrict__ ctx) {
  __shared__ short Kl[2][4096];
  __shared__ short Vl[2][4096];
  int qt = blockIdx.x, bh = blockIdx.y;
  int b = bh >> 2, h = bh & 3;
  const short* Qp = Qb + (size_t)bh * NN * NHD;
  const short* Kp = Kb + (size_t)bh * NN * NHD;
  const short* Vp = Vt + (size_t)bh * NHD * NN;
  int tid = threadIdx.x, w = tid >> 6, lane = tid & 63;
  int q31 = lane & 31, hf = lane >> 5;
  const float THR = 11.5416f;   // 8 * log2(e)

  // Q fragments: B-operand of swapped QK^T. lane holds Q[q31][kd*16 + hf*8 ..+7]
  v8s qf[2][4];
  #pragma unroll
  for (int qb = 0; qb < 2; ++qb)
    #pragma unroll
    for (int kd = 0; kd < 4; ++kd)
      qf[qb][kd] = *(const v8s*)(Qp + (size_t)(qt * 256 + w * 64 + qb * 32 + q31) * 64 + kd * 16 + hf * 8);

  float m_[2] = {-3.0e38f, -3.0e38f};
  float ls[2] = {0.f, 0.f};
  v16f acc[2][2] = {};   // [db][qb], D[d][q]: col=lane&31=q, row d=(reg&3)+8*(reg>>2)+4*hf

  // staging geometry (identical to verified v3): 512 16B-slots per K/V tile
  int slot0 = w * 128 + lane;
  int slot1 = slot0 + 64;
  int r0 = slot0 >> 3, c0 = slot0 & 7;
  int r1 = slot1 >> 3, c1 = slot1 & 7;
  int ko0 = r0 * 64 + ((c0 ^ (r0 & 7)) << 3);
  int ko1 = r1 * 64 + ((c1 ^ (r1 & 7)) << 3);
  size_t vo0 = (size_t)r0 * NN + ((c0 ^ (r0 & 7)) << 3);
  size_t vo1 = (size_t)r1 * NN + ((c1 ^ (r1 & 7)) << 3);

  #define STAGE(t, bfi) do { \
    const short* Kt_ = Kp + (t) * 4096; \
    gload16(Kt_ + ko0, &Kl[bfi][w * 1024]); \
    gload16(Kt_ + ko1, &Kl[bfi][w * 1024 + 512]); \
    const short* Vt_ = Vp + (t) * 64; \
    gload16(Vt_ + vo0, &Vl[bfi][w * 1024]); \
    gload16(Vt_ + vo1, &Vl[bfi][w * 1024 + 512]); \
  } while (0)

  STAGE(0, 0);
  for (int kt = 0; kt < 64; ++kt) {
    int bf = kt & 1;
    if (kt < 63) {
      STAGE(kt + 1, bf ^ 1);
      asm volatile("s_waitcnt vmcnt(4)" ::: "memory");
    } else {
      asm volatile("s_waitcnt vmcnt(0)" ::: "memory");
    }
    __builtin_amdgcn_s_barrier();
    __builtin_amdgcn_sched_barrier(0);
    const short* Kb_ = Kl[bf];
    const short* Vb_ = Vl[bf];
    // K fragments (A-operand): row kv = kvb*32+q31, k = d slice kd*16+hf*8
    v8s kf[2][4];
    #pragma unroll
    for (int kvb = 0; kvb < 2; ++kvb)
      #pragma unroll
      for (int kd = 0; kd < 4; ++kd) {
        int r = kvb * 32 + q31;
        kf[kvb][kd] = *(const v8s*)(Kb_ + r * 64 + (((kd * 2 + hf) ^ (r & 7)) << 3));
      }
    // V^T fragments (A-operand of PV): row d = db*32+q31, k = kv slice s*16+hf*8
    v8s vf[2][4];
    #pragma unroll
    for (int db = 0; db < 2; ++db)
      #pragma unroll
      for (int s = 0; s < 4; ++s) {
        int r = db * 32 + q31;
        vf[db][s] = *(const v8s*)(Vb_ + r * 64 + (((s * 2 + hf) ^ (r & 7)) << 3));
      }
    // S^T = K . Q^T
    v16f st[2][2];
    #pragma unroll
    for (int qb = 0; qb < 2; ++qb)
      #pragma unroll
      for (int kvb = 0; kvb < 2; ++kvb) {
        v16f z = {};
        #pragma unroll
        for (int kd = 0; kd < 4; ++kd)
          z = __builtin_amdgcn_mfma_f32_32x32x16_bf16(kf[kvb][kd], qf[qb][kd], z, 0, 0, 0);
        st[qb][kvb] = z;
      }
    // per q-block: softmax (lane-local, q=lane&31) + PV
    #pragma unroll
    for (int qb = 0; qb < 2; ++qb) {
      float pmax = st[qb][0][0];
      #pragma unroll
      for (int kvb = 0; kvb < 2; ++kvb)
        #pragma unroll
        for (int r = 0; r < 16; ++r) pmax = fmaxf(pmax, st[qb][kvb][r]);
      pmax = fmaxf(pmax, __shfl_xor(pmax, 32, 64));
      if (__any(pmax - m_[qb] > THR)) {
        float mn = fmaxf(m_[qb], pmax);
        float rr = fexp2(m_[qb] - mn);
        m_[qb] = mn;
        #pragma unroll
        for (int db = 0; db < 2; ++db)
          #pragma unroll
          for (int r = 0; r < 16; ++r) acc[db][qb][r] *= rr;
        ls[qb] *= rr;
      }
      float pb[2][16];
      float su = 0.f;
      #pragma unroll
      for (int kvb = 0; kvb < 2; ++kvb)
        #pragma unroll
        for (int r = 0; r < 16; ++r) {
          pb[kvb][r] = fexp2(st[qb][kvb][r] - m_[qb]);
          su += pb[kvb][r];
        }
      ls[qb] += su + __shfl_xor(su, 32, 64);
      // P fragments (B-operand): lane holds P^T[kv slice][q31]; kv = s*16 + hf*8 + i
      #pragma unroll
      for (int s = 0; s < 4; ++s) {
        int kvb = s >> 1, t8 = (s & 1) * 8;
        unsigned a0 = cvt_pk(pb[kvb][t8 + 0], pb[kvb][t8 + 1]);
        unsigned a1 = cvt_pk(pb[kvb][t8 + 2], pb[kvb][t8 + 3]);
        unsigned b0 = cvt_pk(pb[kvb][t8 + 4], pb[kvb][t8 + 5]);
        unsigned b1 = cvt_pk(pb[kvb][t8 + 6], pb[kvb][t8 + 7]);
        unsigned sa0 = (unsigned)__shfl_xor((int)a0, 32, 64);
        unsigned sb0 = (unsigned)__shfl_xor((int)b0, 32, 64);
        unsigned sa1 = (unsigned)__shfl_xor((int)a1, 32, 64);
        unsigned sb1 = (unsigned)__shfl_xor((int)b1, 32, 64);
        unsigned w0 = hf ? sb0 : a0;
        unsigned w2 = hf ? b0 : sa0;
        unsigned w1 = hf ? sb1 : a1;
        unsigned w3 = hf ? b1 : sa1;
        union { unsigned u[4]; v8s v; } pf;
        pf.u[0] = w0; pf.u[1] = w1; pf.u[2] = w2; pf.u[3] = w3;
        #pragma unroll
        for (int db = 0; db < 2; ++db)
          acc[db][qb] = __builtin_amdgcn_mfma_f32_32x32x16_bf16(vf[db][s], pf.v, acc[db][qb], 0, 0, 0);
      }
    }
    __builtin_amdgcn_s_barrier();
    __builtin_amdgcn_sched_barrier(0);
  }
  #undef STAGE
  float rc0 = __builtin_amdgcn_rcpf(ls[0]);
  float rc1 = __builtin_amdgcn_rcpf(ls[1]);
  #pragma unroll
  for (int qb = 0; qb < 2; ++qb) {
    float rc = qb ? rc1 : rc0;
    int n = qt * 256 + w * 64 + qb * 32 + q31;
    #pragma unroll
    for (int db = 0; db < 2; ++db)
      #pragma unroll
      for (int g = 0; g < 4; ++g) {
        v4s o;
        #pragma unroll
        for (int j = 0; j < 4; ++j) o[j] = f2bs(acc[db][qb][g * 4 + j] * rc);
        *(v4s*)(ctx + (size_t)(b * NN + n) * ND + h * 64 + db * 32 + g * 8 + hf * 4) = o;
      }
  }
}

// ---------------- K4: out-proj GEMM (M=16384,K=256,N=256) -> hbuf[:, 256:512]
__global__ __launch_bounds__(256)
void k_oproj(const short* __restrict__ ctx, const short* __restrict__ Wb,
             const float* __restrict__ bias, short* __restrict__ hbuf) {
  __shared__ short Al[64 * 32];
  __shared__ short Bl[64 * 32];
  int mt = blockIdx.x, nt = blockIdx.y, tid = threadIdx.x;
  int w = tid >> 6, lane = tid & 63, lg = lane >> 4, lr = lane & 15;
  int srow = tid >> 2, scol8 = (tid & 3) << 3;
  v4f acc[4] = {};
  for (int kt = 0; kt < 8; ++kt) {
    int k0 = kt * 32;
    v8s av = *(const v8s*)(ctx + (size_t)(mt * 64 + srow) * 256 + k0 + scol8);
    v8s bv = *(const v8s*)(Wb + (size_t)(nt * 64 + srow) * 256 + k0 + scol8);
    __syncthreads();
    *(v8s*)(Al + srow * 32 + (scol8 ^ ((srow & 3) << 3))) = av;
    *(v8s*)(Bl + srow * 32 + (scol8 ^ ((srow & 3) << 3))) = bv;
    __syncthreads();
    int ar = w * 16 + lr;
    v8s af = *(const v8s*)(Al + ar * 32 + ((lg * 8) ^ ((ar & 3) << 3)));
    #pragma unroll
    for (int c = 0; c < 4; ++c) {
      int br = c * 16 + lr;
      v8s bf = *(const v8s*)(Bl + br * 32 + ((lg * 8) ^ ((br & 3) << 3)));
      acc[c] = __builtin_amdgcn_mfma_f32_16x16x32_bf16(af, bf, acc[c], 0, 0, 0);
    }
  }
  #pragma unroll
  for (int c = 0; c < 4; ++c) {
    int gcol = nt * 64 + c * 16 + lr;
    float bb = bias[gcol];
    #pragma unroll
    for (int j = 0; j < 4; ++j) {
      int grow = mt * 64 + w * 16 + lg * 4 + j;
      hbuf[(size_t)grow * 512 + 256 + gcol] = f2bs(acc[c][j] + bb);
    }
  }
}

// ---------------- K5: ffn1 GEMM (M=16384,K=512,N=512) + bias + LN + GELU(tanh) -> h2 bf16
__global__ __launch_bounds__(256)
void k_ffn1(const short* __restrict__ hbuf, const short* __restrict__ Wb,
            const float* __restrict__ bias, const float* __restrict__ ln_g,
            const float* __restrict__ ln_b, short* __restrict__ h2) {
  __shared__ short Al[64 * 32];
  __shared__ short Bl[512 * 32];
  int mt = blockIdx.x, tid = threadIdx.x;
  int w = tid >> 6, lane = tid & 63, lg = lane >> 4, lr = lane & 15;
  int srow = tid >> 2, scol8 = (tid & 3) << 3;
  v4f acc[32] = {};
  for (int kt = 0; kt < 16; ++kt) {
    int k0 = kt * 32;
    v8s av = *(const v8s*)(hbuf + (size_t)(mt * 64 + srow) * 512 + k0 + scol8);
    v8s bvs[8];
    #pragma unroll
    for (int rr = 0; rr < 8; ++rr)
      bvs[rr] = *(const v8s*)(Wb + (size_t)(srow + rr * 64) * 512 + k0 + scol8);
    __syncthreads();
    *(v8s*)(Al + srow * 32 + (scol8 ^ ((srow & 3) << 3))) = av;
    #pragma unroll
    for (int rr = 0; rr < 8; ++rr) {
      int br = srow + rr * 64;
      *(v8s*)(Bl + br * 32 + (scol8 ^ ((br & 3) << 3))) = bvs[rr];
    }
    __syncthreads();
    int ar = w * 16 + lr;
    v8s af = *(const v8s*)(Al + ar * 32 + ((lg * 8) ^ ((ar & 3) << 3)));
    #pragma unroll
    for (int c = 0; c < 32; ++c) {
      int br = c * 16 + lr;
      v8s bf = *(const v8s*)(Bl + br * 32 + ((lg * 8) ^ ((br & 3) << 3)));
      acc[c] = __builtin_amdgcn_mfma_f32_16x16x32_bf16(af, bf, acc[c], 0, 0, 0);
    }
  }
  #pragma unroll
  for (int c = 0; c < 32; ++c) {
    float bb = bias[c * 16 + lr];
    #pragma unroll
    for (int j = 0; j < 4; ++j) acc[c][j] += bb;
  }
  float mu[4], rs[4];
  #pragma unroll
  for (int j = 0; j < 4; ++j) {
    float s = 0.f;
    #pragma unroll
    for (int c = 0; c < 32; ++c) s += acc[c][j];
    #pragma unroll
    for (int mk = 1; mk < 16; mk <<= 1) s += __shfl_xor(s, mk, 64);
    mu[j] = s * (1.0f / 512.0f);
  }
  #pragma unroll
  for (int j = 0; j < 4; ++j) {
    float s = 0.f;
    #pragma unroll
    for (int c = 0; c < 32; ++c) { float d = acc[c][j] - mu[j]; s += d * d; }
    #pragma unroll
    for (int mk = 1; mk < 16; mk <<= 1) s += __shfl_xor(s, mk, 64);
    rs[j] = rsqrtf(s * (1.0f / 512.0f) + 1e-5f);
  }
  #pragma unroll
  for (int c = 0; c < 32; ++c) {
    int col = c * 16 + lr;
    float g = ln_g[col], b2 = ln_b[col];
    #pragma unroll
    for (int j = 0; j < 4; ++j) {
      float y = (acc[c][j] - mu[j]) * rs[j] * g + b2;
      float z = 0.7978845608f * (y + 0.044715f * y * y * y);
      float e = fexp2(2.88539008178f * z);
      float t = (e - 1.0f) * __builtin_amdgcn_rcpf(e + 1.0f);
      float ge = 0.5f * y * (1.0f + t);
      int grow = mt * 64 + w * 16 + lg * 4 + j;
      h2[(size_t)grow * 512 + col] = f2bs_fast(ge);
    }
  }
}

// ---------------- K6: ffn2 GEMM (M=16384,K=512,N=256) + bias + residual -> out fp32
__global__ __launch_bounds__(256)
void k_ffn2(const short* __restrict__ h2, const short* __restrict__ Wb,
             const float* __restrict__ bias, const float* __restrict__ desc,
             float* __restrict__ out) {
  __shared__ short Al[64 * 32];
  __shared__ short Bl[64 * 32];
  int mt = blockIdx.x, nt = blockIdx.y, tid = threadIdx.x;
  int w = tid >> 6, lane = tid & 63, lg = lane >> 4, lr = lane & 15;
  int srow = tid >> 2, scol8 = (tid & 3) << 3;
  v4f acc[4] = {};
  for (int kt = 0; kt < 16; ++kt) {
    int k0 = kt * 32;
    v8s av = *(const v8s*)(h2 + (size_t)(mt * 64 + srow) * 512 + k0 + scol8);
    v8s bv = *(const v8s*)(Wb + (size_t)(nt * 64 + srow) * 512 + k0 + scol8);
    __syncthreads();
    *(v8s*)(Al + srow * 32 + (scol8 ^ ((srow & 3) << 3))) = av;
    *(v8s*)(Bl + srow * 32 + (scol8 ^ ((srow & 3) << 3))) = bv;
    __syncthreads();
    int ar = w * 16 + lr;
    v8s af = *(const v8s*)(Al + ar * 32 + ((lg * 8) ^ ((ar & 3) << 3)));
    #pragma unroll
    for (int c = 0; c < 4; ++c) {
      int br = c * 16 + lr;
      v8s bf = *(const v8s*)(Bl + br * 32 + ((lg * 8) ^ ((br & 3) << 3)));
      acc[c] = __builtin_amdgcn_mfma_f32_16x16x32_bf16(af, bf, acc[c], 0, 0, 0);
    }
  }
  #pragma unroll
  for (int c = 0; c < 4; ++c) {
    int gcol = nt * 64 + c * 16 + lr;
    float bb = bias[gcol];
    #pragma unroll
    for (int j = 0; j < 4; ++j) {
      int grow = mt * 64 + w * 16 + lg * 4 + j;
      out[(size_t)grow * 256 + gcol] = desc[(size_t)grow * 256 + gcol] + acc[c][j] + bb;
    }
  }
}

extern "C" void kernel_launch(void* const* d_in, const int* in_sizes, int n_in,
                              void* d_out, int out_size, void* d_ws, size_t ws_size,
                              hipStream_t stream) {
  const float* desc   = (const float*)d_in[0];
  const float* kp     = (const float*)d_in[1];
  const float* Wqkv_w = (const float*)d_in[2];
  const float* Wqkv_b = (const float*)d_in[3];
  const float* out_w  = (const float*)d_in[4];
  const float* out_b  = (const float*)d_in[5];
  const float* ffn1_w = (const float*)d_in[6];
  const float* ffn1_b = (const float*)d_in[7];
  const float* ln_g   = (const float*)d_in[8];
  const float* ln_b   = (const float*)d_in[9];
  const float* ffn2_w = (const float*)d_in[10];
  const float* ffn2_b = (const float*)d_in[11];
  float* out = (float*)d_out;
  char* ws = (char*)d_ws;

  const size_t MB = 1024 * 1024;
  short* hbuf = (short*)(ws);                 // [16384][512] bf16 (desc | message)
  short* Qb   = (short*)(ws + 16 * MB);       // [B,H,N,64]
  short* Kb   = (short*)(ws + 24 * MB);
  short* Vt   = (short*)(ws + 32 * MB);       // [B,H,64,N] (transposed V)
  short* ctxb = (short*)(ws + 40 * MB);       // [16384][256]
  short* h2   = (short*)(ws + 16 * MB);       // reuses Qb/Kb (dead after attn)
  short* wbuf = (short*)(ws + 48 * MB);
  short* wq = wbuf;                           // [768][256]
  short* wo = wbuf + 196608;                  // [256][256]
  short* w1 = wbuf + 262144;                  // [512][512]
  short* w2 = wbuf + 524288;                  // [256][512]

  k_wcast<<<dim3(320),       dim3(256), 0, stream>>>(Wqkv_w, out_w, ffn1_w, ffn2_w, wbuf);
  k_cast <<<dim3(4096),      dim3(256), 0, stream>>>(desc, hbuf);
  k_qkv  <<<dim3(256, 12),   dim3(256), 0, stream>>>(hbuf, wq, Wqkv_b, kp, Qb, Kb, Vt);
  k_attn <<<dim3(16, 16),    dim3(256), 0, stream>>>(Qb, Kb, Vt, ctxb);
  k_oproj<<<dim3(256, 4),    dim3(256), 0, stream>>>(ctxb, wo, out_b, hbuf);
  k_ffn1 <<<dim3(256),       dim3(256), 0, stream>>>(hbuf, w1, ffn1_b, ln_g, ln_b, h2);
  k_ffn2 <<<dim3(256, 4),    dim3(256), 0, stream>>>(h2, w2, ffn2_b, desc, out);
}

// Round 5
// 189.043 us; speedup vs baseline: 1.1562x; 1.1562x over previous
//
#include <hip/hip_runtime.h>
#include <hip/hip_bf16.h>

typedef __attribute__((ext_vector_type(8))) short v8s;
typedef __attribute__((ext_vector_type(4))) short v4s;
typedef __attribute__((ext_vector_type(4))) float v4f;
typedef __attribute__((ext_vector_type(8))) float v8f;
typedef __attribute__((ext_vector_type(16))) float v16f;

#define NB 4
#define NN 4096
#define ND 256
#define NH 4
#define NHD 64

__device__ __forceinline__ short f2bs(float f) {
  union { __hip_bfloat16 h; short s; } u;
  u.h = __float2bfloat16(f);
  return u.s;
}
__device__ __forceinline__ short f2bs_fast(float f) {
  unsigned u = __float_as_uint(f);
  return (short)((u + 0x7fffu + ((u >> 16) & 1u)) >> 16);
}
__device__ __forceinline__ float fexp2(float x) {
#if __has_builtin(__builtin_amdgcn_exp2f)
  return __builtin_amdgcn_exp2f(x);
#else
  return exp2f(x);
#endif
}
__device__ __forceinline__ unsigned cvt_pk(float lo, float hi) {
  unsigned r;
  asm("v_cvt_pk_bf16_f32 %0, %1, %2" : "=v"(r) : "v"(lo), "v"(hi));
  return r;
}
// v_permlane32_swap_b32: a[32:63] <-> b[0:31]. After: lane<32 {a=own a, b=a of lane+32}
// is wrong reading; correct: a_new[i<32]=a_old[i], a_new[i>=32]=b_old[i-32];
//                            b_new[i<32]=a_old[i+32], b_new[i>=32]=b_old[i].
__device__ __forceinline__ void pl32(unsigned &a, unsigned &b) {
  asm("v_permlane32_swap_b32 %0, %1" : "+v"(a), "+v"(b));
}
// value of x from the partner lane (lane ^ 32), via permlane (VALU, no LDS pipe)
__device__ __forceinline__ float xpick(float x, int hf) {
  unsigned t = __float_as_uint(x), u = t;
  pl32(t, u);
  return __uint_as_float(hf ? t : u);
}

__device__ __forceinline__ void gload16(const short* g, short* l) {
  __builtin_amdgcn_global_load_lds((const __attribute__((address_space(1))) void*)g,
                                   (__attribute__((address_space(3))) void*)l, 16, 0, 0);
}

// ---------------- K0: cast descriptors fp32 -> bf16 into hbuf[:, 0:256] (ld 512)
__global__ void k_cast(const float* __restrict__ desc, short* __restrict__ hbuf) {
  int i = blockIdx.x * blockDim.x + threadIdx.x;
  const v4f* src = (const v4f*)desc;
  v4f v = src[i];
  int e0 = i << 2;
  int row = e0 >> 8;
  int col = e0 & 255;
  v4s o;
  #pragma unroll
  for (int j = 0; j < 4; ++j) o[j] = f2bs(v[j]);
  *(v4s*)(hbuf + row * 512 + col) = o;
}

// ---------------- K0b: cast weights fp32 -> bf16 (Wqkv | out_w | ffn1_w | ffn2_w)
__global__ void k_wcast(const float* __restrict__ a, const float* __restrict__ b,
                        const float* __restrict__ c, const float* __restrict__ d,
                        short* __restrict__ o) {
  int i = (blockIdx.x * 256 + threadIdx.x) * 8;
  const float* s; int off;
  if (i < 196608)      { s = a; off = 0; }
  else if (i < 262144) { s = b; off = 196608; }
  else if (i < 524288) { s = c; off = 262144; }
  else                 { s = d; off = 524288; }
  v8f v = *(const v8f*)(s + (i - off));
  v8s r;
  #pragma unroll
  for (int j = 0; j < 8; ++j) r[j] = f2bs(v[j]);
  *(v8s*)(o + i) = r;
}

// ---------------- K1: QKV GEMM + fused RoPE (permuted col order)
__global__ __launch_bounds__(256)
void k_qkv(const short* __restrict__ hbuf, const short* __restrict__ Wb,
           const float* __restrict__ bias, const float* __restrict__ kp,
           short* __restrict__ Qb, short* __restrict__ Kb, short* __restrict__ Vt) {
  __shared__ short Al[64 * 32];
  __shared__ short Bl[64 * 32];
  int mt = blockIdx.x, nt = blockIdx.y, tid = threadIdx.x;
  int w = tid >> 6, lane = tid & 63, lg = lane >> 4, lr = lane & 15;
  int srow = tid >> 2, scol8 = (tid & 3) << 3;
  int t_ = nt >> 2, h_ = nt & 3;
  int dS = (nt * 64 + srow) & 63;
  int wrow = h_ * 192 + dS * 3 + t_;
  v4f acc[4] = {};
  for (int kt = 0; kt < 8; ++kt) {
    int k0 = kt * 32;
    v8s av = *(const v8s*)(hbuf + (size_t)(mt * 64 + srow) * 512 + k0 + scol8);
    v8s bv = *(const v8s*)(Wb + (size_t)wrow * 256 + k0 + scol8);
    __syncthreads();
    *(v8s*)(Al + srow * 32 + (scol8 ^ ((srow & 3) << 3))) = av;
    *(v8s*)(Bl + srow * 32 + (scol8 ^ ((srow & 3) << 3))) = bv;
    __syncthreads();
    int ar = w * 16 + lr;
    v8s af = *(const v8s*)(Al + ar * 32 + ((lg * 8) ^ ((ar & 3) << 3)));
    #pragma unroll
    for (int c = 0; c < 4; ++c) {
      int br = c * 16 + lr;
      v8s bf = *(const v8s*)(Bl + br * 32 + ((lg * 8) ^ ((br & 3) << 3)));
      acc[c] = __builtin_amdgcn_mfma_f32_16x16x32_bf16(af, bf, acc[c], 0, 0, 0);
    }
  }
  int grow0 = mt * 64 + w * 16 + lg * 4;
  int b_ = grow0 >> 12, n0 = grow0 & 4095;
  if (t_ == 2) {
    #pragma unroll
    for (int c = 0; c < 4; ++c) {
      int d = c * 16 + lr;
      float bb = bias[h_ * 192 + d * 3 + 2];
      v4s pw;
      #pragma unroll
      for (int j = 0; j < 4; ++j) pw[j] = f2bs(acc[c][j] + bb);
      *(v4s*)(Vt + ((size_t)((b_ * NH + h_) * NHD + d) * NN + n0)) = pw;
    }
  } else {
    float qsc = (t_ == 0) ? 0.125f * 1.44269504088896340736f : 1.0f;
    short* dst = (t_ == 0) ? Qb : Kb;
    #pragma unroll
    for (int c = 0; c < 4; ++c) {
      int d = c * 16 + lr;
      float bb = bias[h_ * 192 + d * 3 + t_];
      #pragma unroll
      for (int j = 0; j < 4; ++j) {
        float x = acc[c][j] + bb;
        float xp = __shfl_xor(x, 1, 64);
        int n_ = n0 + j;
        float cs = kp[((size_t)b_ * NN + n_) * 64 + d];
        float sn = kp[((size_t)(NB + b_) * NN + n_) * 64 + d];
        float ov = (d & 1) ? (x * cs + xp * sn) : (x * cs - xp * sn);
        dst[((size_t)((b_ * NH + h_) * NN + n_)) * 64 + d] = f2bs(ov * qsc);
      }
    }
  }
}

// ---------------- K3: flash attention v5. grid (16,16), 512 threads = 8 waves, 32 q/wave.
// 2 waves/SIMD for latency hiding; permlane32_swap for all cross-half ops; tree reductions.
__global__ __launch_bounds__(512, 2)
void k_attn(const short* __restrict__ Qb, const short* __restrict__ Kb,
            const short* __restrict__ Vt, short* __restrict__ ctx) {
  __shared__ short Kl[2][4096];
  __shared__ short Vl[2][4096];
  int qt = blockIdx.x, bh = blockIdx.y;
  int b = bh >> 2, h = bh & 3;
  const short* Qp = Qb + (size_t)bh * NN * NHD;
  const short* Kp = Kb + (size_t)bh * NN * NHD;
  const short* Vp = Vt + (size_t)bh * NHD * NN;
  int tid = threadIdx.x, w = tid >> 6, lane = tid & 63;
  int q31 = lane & 31, hf = lane >> 5;
  const float THR = 11.5416f;   // 8 * log2(e)

  v8s qf[4];
  {
    int qrow = qt * 256 + w * 32 + q31;
    #pragma unroll
    for (int kd = 0; kd < 4; ++kd)
      qf[kd] = *(const v8s*)(Qp + (size_t)qrow * 64 + kd * 16 + hf * 8);
  }
  float m = -3.0e38f, ls = 0.f;
  v16f acc[2] = {};   // [db], D[d][q]: col=lane&31=q, d=(r&3)+8*(r>>2)+4*hf + 32*db

  // staging: 512 16B-slots per K/V tile; wave w covers slots [w*64, w*64+64)
  int slot = w * 64 + lane;
  int r0 = slot >> 3, c0 = slot & 7;
  int ko0 = r0 * 64 + ((c0 ^ (r0 & 7)) << 3);
  size_t vo0 = (size_t)r0 * NN + ((c0 ^ (r0 & 7)) << 3);

  #define STAGE(t, bfi) do { \
    gload16(Kp + (size_t)(t) * 4096 + ko0, &Kl[bfi][w * 512]); \
    gload16(Vp + (size_t)(t) * 64 + vo0, &Vl[bfi][w * 512]); \
  } while (0)

  STAGE(0, 0);
  for (int kt = 0; kt < 64; ++kt) {
    int bf = kt & 1;
    if (kt < 63) {
      STAGE(kt + 1, bf ^ 1);
      asm volatile("s_waitcnt vmcnt(2)" ::: "memory");
    } else {
      asm volatile("s_waitcnt vmcnt(0)" ::: "memory");
    }
    __builtin_amdgcn_s_barrier();
    __builtin_amdgcn_sched_barrier(0);
    const short* Kb_ = Kl[bf];
    const short* Vb_ = Vl[bf];
    v8s kf[2][4], vf[2][4];
    #pragma unroll
    for (int kvb = 0; kvb < 2; ++kvb) {
      int r = kvb * 32 + q31;
      int sw = r & 7;
      #pragma unroll
      for (int kd = 0; kd < 4; ++kd)
        kf[kvb][kd] = *(const v8s*)(Kb_ + r * 64 + (((kd * 2 + hf) ^ sw) << 3));
    }
    #pragma unroll
    for (int db = 0; db < 2; ++db) {
      int r = db * 32 + q31;
      int sw = r & 7;
      #pragma unroll
      for (int s = 0; s < 4; ++s)
        vf[db][s] = *(const v8s*)(Vb_ + r * 64 + (((s * 2 + hf) ^ sw) << 3));
    }
    // S^T = K . Q^T
    v16f st[2];
    __builtin_amdgcn_s_setprio(1);
    #pragma unroll
    for (int kvb = 0; kvb < 2; ++kvb) {
      v16f z = {};
      #pragma unroll
      for (int kd = 0; kd < 4; ++kd)
        z = __builtin_amdgcn_mfma_f32_32x32x16_bf16(kf[kvb][kd], qf[kd], z, 0, 0, 0);
      st[kvb] = z;
    }
    __builtin_amdgcn_s_setprio(0);
    // tree row-max (lane-local; q = lane&31)
    float mx[8];
    #pragma unroll
    for (int i = 0; i < 8; ++i)
      mx[i] = fmaxf(fmaxf(st[0][i], st[0][i + 8]), fmaxf(st[1][i], st[1][i + 8]));
    #pragma unroll
    for (int off = 4; off >= 1; off >>= 1)
      #pragma unroll
      for (int i = 0; i < off; ++i) mx[i] = fmaxf(mx[i], mx[i + off]);
    float pmax = fmaxf(mx[0], xpick(mx[0], hf));
    // defer-max rescale
    if (__any(pmax - m > THR)) {
      float mn = fmaxf(m, pmax);
      float rr = fexp2(m - mn);
      m = mn;
      #pragma unroll
      for (int db = 0; db < 2; ++db)
        #pragma unroll
        for (int r = 0; r < 16; ++r) acc[db][r] *= rr;
      ls *= rr;
    }
    // P = exp2(S - m) in place
    #pragma unroll
    for (int kvb = 0; kvb < 2; ++kvb)
      #pragma unroll
      for (int r = 0; r < 16; ++r) st[kvb][r] = fexp2(st[kvb][r] - m);
    // tree row-sum
    float sm[8];
    #pragma unroll
    for (int i = 0; i < 8; ++i)
      sm[i] = (st[0][i] + st[0][i + 8]) + (st[1][i] + st[1][i + 8]);
    #pragma unroll
    for (int off = 4; off >= 1; off >>= 1)
      #pragma unroll
      for (int i = 0; i < off; ++i) sm[i] += sm[i + off];
    ls += sm[0] + xpick(sm[0], hf);
    // PV: per k-slice s build P-fragment via cvt_pk + permlane32_swap
    __builtin_amdgcn_s_setprio(1);
    #pragma unroll
    for (int s = 0; s < 4; ++s) {
      int kvb = s >> 1, rb = (s & 1) * 8;
      unsigned u0 = cvt_pk(st[kvb][rb + 0], st[kvb][rb + 1]);
      unsigned u1 = cvt_pk(st[kvb][rb + 2], st[kvb][rb + 3]);
      unsigned u2 = cvt_pk(st[kvb][rb + 4], st[kvb][rb + 5]);
      unsigned u3 = cvt_pk(st[kvb][rb + 6], st[kvb][rb + 7]);
      pl32(u0, u2);   // -> dword0 (all lanes), dword2 (all lanes)
      pl32(u1, u3);   // -> dword1, dword3
      union { unsigned u[4]; v8s v; } pf;
      pf.u[0] = u0; pf.u[1] = u1; pf.u[2] = u2; pf.u[3] = u3;
      #pragma unroll
      for (int db = 0; db < 2; ++db)
        acc[db] = __builtin_amdgcn_mfma_f32_32x32x16_bf16(vf[db][s], pf.v, acc[db], 0, 0, 0);
    }
    __builtin_amdgcn_s_setprio(0);
    __builtin_amdgcn_s_barrier();
    __builtin_amdgcn_sched_barrier(0);
  }
  #undef STAGE
  float rc = __builtin_amdgcn_rcpf(ls);
  int n = qt * 256 + w * 32 + q31;
  #pragma unroll
  for (int db = 0; db < 2; ++db)
    #pragma unroll
    for (int g = 0; g < 4; ++g) {
      v4s o;
      #pragma unroll
      for (int j = 0; j < 4; ++j) o[j] = f2bs(acc[db][g * 4 + j] * rc);
      *(v4s*)(ctx + (size_t)(b * NN + n) * ND + h * 64 + db * 32 + g * 8 + hf * 4) = o;
    }
}

// ---------------- K4: out-proj GEMM (M=16384,K=256,N=256) -> hbuf[:, 256:512]
__global__ __launch_bounds__(256)
void k_oproj(const short* __restrict__ ctx, const short* __restrict__ Wb,
             const float* __restrict__ bias, short* __restrict__ hbuf) {
  __shared__ short Al[64 * 32];
  __shared__ short Bl[64 * 32];
  int mt = blockIdx.x, nt = blockIdx.y, tid = threadIdx.x;
  int w = tid >> 6, lane = tid & 63, lg = lane >> 4, lr = lane & 15;
  int srow = tid >> 2, scol8 = (tid & 3) << 3;
  v4f acc[4] = {};
  for (int kt = 0; kt < 8; ++kt) {
    int k0 = kt * 32;
    v8s av = *(const v8s*)(ctx + (size_t)(mt * 64 + srow) * 256 + k0 + scol8);
    v8s bv = *(const v8s*)(Wb + (size_t)(nt * 64 + srow) * 256 + k0 + scol8);
    __syncthreads();
    *(v8s*)(Al + srow * 32 + (scol8 ^ ((srow & 3) << 3))) = av;
    *(v8s*)(Bl + srow * 32 + (scol8 ^ ((srow & 3) << 3))) = bv;
    __syncthreads();
    int ar = w * 16 + lr;
    v8s af = *(const v8s*)(Al + ar * 32 + ((lg * 8) ^ ((ar & 3) << 3)));
    #pragma unroll
    for (int c = 0; c < 4; ++c) {
      int br = c * 16 + lr;
      v8s bf = *(const v8s*)(Bl + br * 32 + ((lg * 8) ^ ((br & 3) << 3)));
      acc[c] = __builtin_amdgcn_mfma_f32_16x16x32_bf16(af, bf, acc[c], 0, 0, 0);
    }
  }
  #pragma unroll
  for (int c = 0; c < 4; ++c) {
    int gcol = nt * 64 + c * 16 + lr;
    float bb = bias[gcol];
    #pragma unroll
    for (int j = 0; j < 4; ++j) {
      int grow = mt * 64 + w * 16 + lg * 4 + j;
      hbuf[(size_t)grow * 512 + 256 + gcol] = f2bs(acc[c][j] + bb);
    }
  }
}

// ---------------- K5: ffn1 GEMM (M=16384,K=512,N=512) + bias + LN + GELU(tanh) -> h2 bf16
__global__ __launch_bounds__(256)
void k_ffn1(const short* __restrict__ hbuf, const short* __restrict__ Wb,
            const float* __restrict__ bias, const float* __restrict__ ln_g,
            const float* __restrict__ ln_b, short* __restrict__ h2) {
  __shared__ short Al[64 * 32];
  __shared__ short Bl[512 * 32];
  int mt = blockIdx.x, tid = threadIdx.x;
  int w = tid >> 6, lane = tid & 63, lg = lane >> 4, lr = lane & 15;
  int srow = tid >> 2, scol8 = (tid & 3) << 3;
  v4f acc[32] = {};
  for (int kt = 0; kt < 16; ++kt) {
    int k0 = kt * 32;
    v8s av = *(const v8s*)(hbuf + (size_t)(mt * 64 + srow) * 512 + k0 + scol8);
    v8s bvs[8];
    #pragma unroll
    for (int rr = 0; rr < 8; ++rr)
      bvs[rr] = *(const v8s*)(Wb + (size_t)(srow + rr * 64) * 512 + k0 + scol8);
    __syncthreads();
    *(v8s*)(Al + srow * 32 + (scol8 ^ ((srow & 3) << 3))) = av;
    #pragma unroll
    for (int rr = 0; rr < 8; ++rr) {
      int br = srow + rr * 64;
      *(v8s*)(Bl + br * 32 + (scol8 ^ ((br & 3) << 3))) = bvs[rr];
    }
    __syncthreads();
    int ar = w * 16 + lr;
    v8s af = *(const v8s*)(Al + ar * 32 + ((lg * 8) ^ ((ar & 3) << 3)));
    #pragma unroll
    for (int c = 0; c < 32; ++c) {
      int br = c * 16 + lr;
      v8s bf = *(const v8s*)(Bl + br * 32 + ((lg * 8) ^ ((br & 3) << 3)));
      acc[c] = __builtin_amdgcn_mfma_f32_16x16x32_bf16(af, bf, acc[c], 0, 0, 0);
    }
  }
  #pragma unroll
  for (int c = 0; c < 32; ++c) {
    float bb = bias[c * 16 + lr];
    #pragma unroll
    for (int j = 0; j < 4; ++j) acc[c][j] += bb;
  }
  float mu[4], rs[4];
  #pragma unroll
  for (int j = 0; j < 4; ++j) {
    float s = 0.f;
    #pragma unroll
    for (int c = 0; c < 32; ++c) s += acc[c][j];
    #pragma unroll
    for (int mk = 1; mk < 16; mk <<= 1) s += __shfl_xor(s, mk, 64);
    mu[j] = s * (1.0f / 512.0f);
  }
  #pragma unroll
  for (int j = 0; j < 4; ++j) {
    float s = 0.f;
    #pragma unroll
    for (int c = 0; c < 32; ++c) { float d = acc[c][j] - mu[j]; s += d * d; }
    #pragma unroll
    for (int mk = 1; mk < 16; mk <<= 1) s += __shfl_xor(s, mk, 64);
    rs[j] = rsqrtf(s * (1.0f / 512.0f) + 1e-5f);
  }
  #pragma unroll
  for (int c = 0; c < 32; ++c) {
    int col = c * 16 + lr;
    float g = ln_g[col], b2 = ln_b[col];
    #pragma unroll
    for (int j = 0; j < 4; ++j) {
      float y = (acc[c][j] - mu[j]) * rs[j] * g + b2;
      float z = 0.7978845608f * (y + 0.044715f * y * y * y);
      float e = fexp2(2.88539008178f * z);
      float t = (e - 1.0f) * __builtin_amdgcn_rcpf(e + 1.0f);
      float ge = 0.5f * y * (1.0f + t);
      int grow = mt * 64 + w * 16 + lg * 4 + j;
      h2[(size_t)grow * 512 + col] = f2bs_fast(ge);
    }
  }
}

// ---------------- K6: ffn2 GEMM (M=16384,K=512,N=256) + bias + residual -> out fp32
__global__ __launch_bounds__(256)
void k_ffn2(const short* __restrict__ h2, const short* __restrict__ Wb,
             const float* __restrict__ bias, const float* __restrict__ desc,
             float* __restrict__ out) {
  __shared__ short Al[64 * 32];
  __shared__ short Bl[64 * 32];
  int mt = blockIdx.x, nt = blockIdx.y, tid = threadIdx.x;
  int w = tid >> 6, lane = tid & 63, lg = lane >> 4, lr = lane & 15;
  int srow = tid >> 2, scol8 = (tid & 3) << 3;
  v4f acc[4] = {};
  for (int kt = 0; kt < 16; ++kt) {
    int k0 = kt * 32;
    v8s av = *(const v8s*)(h2 + (size_t)(mt * 64 + srow) * 512 + k0 + scol8);
    v8s bv = *(const v8s*)(Wb + (size_t)(nt * 64 + srow) * 512 + k0 + scol8);
    __syncthreads();
    *(v8s*)(Al + srow * 32 + (scol8 ^ ((srow & 3) << 3))) = av;
    *(v8s*)(Bl + srow * 32 + (scol8 ^ ((srow & 3) << 3))) = bv;
    __syncthreads();
    int ar = w * 16 + lr;
    v8s af = *(const v8s*)(Al + ar * 32 + ((lg * 8) ^ ((ar & 3) << 3)));
    #pragma unroll
    for (int c = 0; c < 4; ++c) {
      int br = c * 16 + lr;
      v8s bf = *(const v8s*)(Bl + br * 32 + ((lg * 8) ^ ((br & 3) << 3)));
      acc[c] = __builtin_amdgcn_mfma_f32_16x16x32_bf16(af, bf, acc[c], 0, 0, 0);
    }
  }
  #pragma unroll
  for (int c = 0; c < 4; ++c) {
    int gcol = nt * 64 + c * 16 + lr;
    float bb = bias[gcol];
    #pragma unroll
    for (int j = 0; j < 4; ++j) {
      int grow = mt * 64 + w * 16 + lg * 4 + j;
      out[(size_t)grow * 256 + gcol] = desc[(size_t)grow * 256 + gcol] + acc[c][j] + bb;
    }
  }
}

extern "C" void kernel_launch(void* const* d_in, const int* in_sizes, int n_in,
                              void* d_out, int out_size, void* d_ws, size_t ws_size,
                              hipStream_t stream) {
  const float* desc   = (const float*)d_in[0];
  const float* kp     = (const float*)d_in[1];
  const float* Wqkv_w = (const float*)d_in[2];
  const float* Wqkv_b = (const float*)d_in[3];
  const float* out_w  = (const float*)d_in[4];
  const float* out_b  = (const float*)d_in[5];
  const float* ffn1_w = (const float*)d_in[6];
  const float* ffn1_b = (const float*)d_in[7];
  const float* ln_g   = (const float*)d_in[8];
  const float* ln_b   = (const float*)d_in[9];
  const float* ffn2_w = (const float*)d_in[10];
  const float* ffn2_b = (const float*)d_in[11];
  float* out = (float*)d_out;
  char* ws = (char*)d_ws;

  const size_t MB = 1024 * 1024;
  short* hbuf = (short*)(ws);                 // [16384][512] bf16 (desc | message)
  short* Qb   = (short*)(ws + 16 * MB);       // [B,H,N,64]
  short* Kb   = (short*)(ws + 24 * MB);
  short* Vt   = (short*)(ws + 32 * MB);       // [B,H,64,N] (transposed V)
  short* ctxb = (short*)(ws + 40 * MB);       // [16384][256]
  short* h2   = (short*)(ws + 16 * MB);       // reuses Qb/Kb (dead after attn)
  short* wbuf = (short*)(ws + 48 * MB);
  short* wq = wbuf;                           // [768][256]
  short* wo = wbuf + 196608;                  // [256][256]
  short* w1 = wbuf + 262144;                  // [512][512]
  short* w2 = wbuf + 524288;                  // [256][512]

  k_wcast<<<dim3(320),       dim3(256), 0, stream>>>(Wqkv_w, out_w, ffn1_w, ffn2_w, wbuf);
  k_cast <<<dim3(4096),      dim3(256), 0, stream>>>(desc, hbuf);
  k_qkv  <<<dim3(256, 12),   dim3(256), 0, stream>>>(hbuf, wq, Wqkv_b, kp, Qb, Kb, Vt);
  k_attn <<<dim3(16, 16),    dim3(512), 0, stream>>>(Qb, Kb, Vt, ctxb);
  k_oproj<<<dim3(256, 4),    dim3(256), 0, stream>>>(ctxb, wo, out_b, hbuf);
  k_ffn1 <<<dim3(256),       dim3(256), 0, stream>>>(hbuf, w1, ffn1_b, ln_g, ln_b, h2);
  k_ffn2 <<<dim3(256, 4),    dim3(256), 0, stream>>>(h2, w2, ffn2_b, desc, out);
}